// Round 5
// baseline (112.487 us; speedup 1.0000x reference)
//
#include <hip/hip_runtime.h>
#include <math.h>

#define TEMP_F 0.07f
#define NCON 20
#define LDIM 512
#define NROWS 32768
#define NSEL 16384

// ws layout (floats):
// [2048 .. 2048+2*NROWS)  t2[r] = float2{ t_sz(r), t_nsz(r) }  (256 KB table)
//   t_b(r) = log( sum_{j kept_b} exp(sim[r,j]/T) ) - <hg_r, ebar_b>/(T*||hg_r||)

__device__ inline float dot4(float4 a, float4 b) {
    return a.x * b.x + a.y * b.y + a.z * b.z + a.w * b.w;
}
__device__ inline float4 add4(float4 a, float4 b) {
    return make_float4(a.x + b.x, a.y + b.y, a.z + b.z, a.w + b.w);
}
__device__ inline float4 scale4(float4 a, float s) {
    return make_float4(a.x * s, a.y * s, a.z * s, a.w * s);
}

// ---------------------------------------------------------------------------
// Kernel 1: single streaming pass, prep folded in. 4096 blocks x 256 threads
// = 16384 waves, 2 rows per wave, UNCONDITIONAL (no data-dependent branches).
// Each wave builds its ebar fragment from all_emb (40 KB, L1-warm after the
// first wave per CU: 20 float4 loads, hoisted once per wave) and the keep
// masks from Psz/Pnsz (wave-uniform scalar loads + bit ops). Then streams its
// 2 hg rows + sim rows, butterfly-reduces 10 values, lane 0 stores one
// float4 = both rows' {t_sz, t_nsz}.
// ---------------------------------------------------------------------------
__global__ __launch_bounds__(256) void stream_kernel(const float* __restrict__ hg,
                                                     const float* __restrict__ sim,
                                                     const float* __restrict__ all_emb,
                                                     const int* __restrict__ Psz,
                                                     const int* __restrict__ Pnsz,
                                                     float* __restrict__ ws,
                                                     float* __restrict__ out) {
    const int wg   = (blockIdx.x * 256 + threadIdx.x) >> 6;  // global wave id
    const int lane = threadIdx.x & 63;
    const int r0   = wg * 2;                                 // rows r0, r0+1

    // out is poisoned before every launch; gather_kernel atomics need 0.
    // Dispatch barrier orders this store before any gather atomic.
    if (blockIdx.x == 0 && threadIdx.x == 0) out[0] = 0.f;

    // ---- per-wave prep: ebar fragments + keep masks (once per 2 rows) ----
    const float4* emb4 = (const float4*)all_emb;  // concept c: emb4[c*128 ...]
    float4 es0 = make_float4(0, 0, 0, 0), es1 = es0, en0 = es0, en1 = es0;
    unsigned msz = (1u << NCON) - 1u, mnsz = (1u << NCON) - 1u;
#pragma unroll
    for (int k = 0; k < 5; ++k) {
        const int cs = Psz[k], cn = Pnsz[k];   // wave-uniform scalar loads
        const float4* ps = emb4 + cs * (LDIM / 4) + lane * 2;
        const float4* pn = emb4 + cn * (LDIM / 4) + lane * 2;
        es0 = add4(es0, ps[0]);  es1 = add4(es1, ps[1]);
        en0 = add4(en0, pn[0]);  en1 = add4(en1, pn[1]);
        msz  &= ~(1u << cs);
        mnsz &= ~(1u << cn);
    }
    es0 = scale4(es0, 0.2f); es1 = scale4(es1, 0.2f);  // mean over 5
    en0 = scale4(en0, 0.2f); en1 = scale4(en1, 0.2f);  // (duplicates counted)

    // ---- unconditional streaming loads: 2 rows, all issued up front ----
    const float4* rp = (const float4*)hg + (size_t)r0 * (LDIM / 4) + lane * 2;
    const float4 aA0 = rp[0];
    const float4 aA1 = rp[1];
    const float4 aB0 = rp[LDIM / 4];
    const float4 aB1 = rp[LDIM / 4 + 1];
    const bool  c20 = lane < NCON;
    const float svA = c20 ? sim[(size_t)r0 * NCON + lane]       : 0.f;
    const float svB = c20 ? sim[(size_t)(r0 + 1) * NCON + lane] : 0.f;

    const float invT = 1.0f / TEMP_F;

    float ssA = dot4(aA0, aA0) + dot4(aA1, aA1);
    float dsA = dot4(aA0, es0) + dot4(aA1, es1);
    float dnA = dot4(aA0, en0) + dot4(aA1, en1);
    float ssB = dot4(aB0, aB0) + dot4(aB1, aB1);
    float dsB = dot4(aB0, es0) + dot4(aB1, es1);
    float dnB = dot4(aB0, en0) + dot4(aB1, en1);

    const float exA = expf(svA * invT);
    const float exB = expf(svB * invT);
    const bool ks = c20 && (msz  & (1u << lane));
    const bool kn = c20 && (mnsz & (1u << lane));
    float esA = ks ? exA : 0.f, enA = kn ? exA : 0.f;
    float esB = ks ? exB : 0.f, enB = kn ? exB : 0.f;

#pragma unroll
    for (int off = 32; off; off >>= 1) {
        ssA += __shfl_xor(ssA, off);  ssB += __shfl_xor(ssB, off);
        dsA += __shfl_xor(dsA, off);  dsB += __shfl_xor(dsB, off);
        dnA += __shfl_xor(dnA, off);  dnB += __shfl_xor(dnB, off);
        esA += __shfl_xor(esA, off);  esB += __shfl_xor(esB, off);
        enA += __shfl_xor(enA, off);  enB += __shfl_xor(enB, off);
    }

    if (lane == 0) {
        const float rnA = invT / fmaxf(sqrtf(ssA), 1e-12f);
        const float rnB = invT / fmaxf(sqrtf(ssB), 1e-12f);
        // t2 for rows r0, r0+1 in one 16B store
        ((float4*)(ws + 2048))[wg] = make_float4(logf(esA) - dsA * rnA,
                                                 logf(enA) - dnA * rnA,
                                                 logf(esB) - dsB * rnB,
                                                 logf(enB) - dnB * rnB);
    }
}

// ---------------------------------------------------------------------------
// Kernel 2: selection gather + reduce. 128 blocks x 256 = 32768 threads,
// one selection each (sz for t<16384, nsz above — wave-uniform split).
// Gather is a single 4B read from the L2/L3-resident 256 KB table.
// 128 same-address atomics total (measured free in r0).
// ---------------------------------------------------------------------------
__global__ __launch_bounds__(256) void gather_kernel(const int* __restrict__ sz_idx,
                                                     const int* __restrict__ nsz_idx,
                                                     const float* __restrict__ ws,
                                                     float* __restrict__ out) {
    const float2* t2 = (const float2*)(ws + 2048);
    const int t = blockIdx.x * 256 + threadIdx.x;

    float v;
    if (t < NSEL) v = t2[sz_idx[t]].x;
    else          v = t2[nsz_idx[t - NSEL]].y;

#pragma unroll
    for (int off = 32; off; off >>= 1) v += __shfl_xor(v, off);

    __shared__ float red[4];
    const int lane = threadIdx.x & 63;
    const int w    = threadIdx.x >> 6;
    if (lane == 0) red[w] = v;
    __syncthreads();
    if (threadIdx.x == 0)
        atomicAdd(out, (red[0] + red[1] + red[2] + red[3]) * (1.0f / NSEL));
}

extern "C" void kernel_launch(void* const* d_in, const int* in_sizes, int n_in,
                              void* d_out, int out_size, void* d_ws, size_t ws_size,
                              hipStream_t stream) {
    const float* hg      = (const float*)d_in[0];
    const float* hg_corr = (const float*)d_in[1];
    const float* all_emb = (const float*)d_in[2];
    const int*   sz_idx  = (const int*)d_in[3];
    const int*   nsz_idx = (const int*)d_in[4];
    const int*   Psz     = (const int*)d_in[5];
    const int*   Pnsz    = (const int*)d_in[6];
    float* out = (float*)d_out;
    float* ws  = (float*)d_ws;

    stream_kernel<<<4096, 256, 0, stream>>>(hg, hg_corr, all_emb, Psz, Pnsz, ws, out);
    gather_kernel<<<128, 256, 0, stream>>>(sz_idx, nsz_idx, ws, out);
}